// Round 3
// baseline (89.672 us; speedup 1.0000x reference)
//
#include <hip/hip_runtime.h>
#include <hip/hip_bf16.h>

typedef float f32x4 __attribute__((ext_vector_type(4)));
typedef short bf16x8 __attribute__((ext_vector_type(8)));

constexpr int NB = 16, LQ = 2048, LK = 2048, D = 128, DV = 128;
constexpr int KVBLK = 64, NT = LK / KVBLK;
constexpr float SCALE = 0.08838834764831843f;   // 1/sqrt(128)
constexpr float LOG2E = 1.4426950408889634f;
constexpr float QSCALE = SCALE * LOG2E;         // softmax in log2 domain

// ---------- helpers ----------
__device__ __forceinline__ unsigned short f2bfs(float f) {
  __hip_bfloat16 h = __float2bfloat16(f);      // RNE
  return __builtin_bit_cast(unsigned short, h);
}

__device__ __forceinline__ unsigned short f2bf(float f) {
  unsigned int u = __float_as_uint(f);
  u += 0x7FFFu + ((u >> 16) & 1u);
  return (unsigned short)(u >> 16);
}

__device__ __forceinline__ int swz2(int row) {
  return (row ^ (row >> 1) ^ (row >> 3)) & 7;
}

typedef const __attribute__((address_space(1))) void* gas1_t;
typedef __attribute__((address_space(3))) void* las3_t;
__device__ __forceinline__ void gload16(const void* g, void* l) {
  __builtin_amdgcn_global_load_lds((gas1_t)g, (las3_t)l, 16, 0, 0);
}

// ---------- prepass: fp32 -> bf16 ----------
__global__ __launch_bounds__(256) void conv_bf16(const float* __restrict__ in,
                                                 unsigned short* __restrict__ out,
                                                 float scale) {
  int i = blockIdx.x * 256 + threadIdx.x;
  f32x4 a = ((const f32x4*)in)[2 * i];
  f32x4 b = ((const f32x4*)in)[2 * i + 1];
  bf16x8 r;
  #pragma unroll
  for (int j = 0; j < 4; ++j) {
    r[j]     = (short)f2bfs(a[j] * scale);
    r[4 + j] = (short)f2bfs(b[j] * scale);
  }
  ((bf16x8*)out)[i] = r;
}

// ---------- prepass: V[b][k][dv] fp32 -> Vt[b][dv][k] bf16 ----------
__global__ __launch_bounds__(256) void conv_vt(const float* __restrict__ v,
                                               unsigned short* __restrict__ vt) {
  __shared__ __align__(16) unsigned short tb[64 * 64];
  const int tid = threadIdx.x;
  const int k0 = blockIdx.x * 64, dv0 = blockIdx.y * 64, b = blockIdx.z;
  {
    const int kk = tid >> 2, dd0 = (tid & 3) * 16;
    const float* src = v + ((long)(b * LK + k0 + kk)) * DV + dv0 + dd0;
    f32x4 a0 = ((const f32x4*)src)[0];
    f32x4 a1 = ((const f32x4*)src)[1];
    f32x4 a2 = ((const f32x4*)src)[2];
    f32x4 a3 = ((const f32x4*)src)[3];
    bf16x8 r0, r1;
    #pragma unroll
    for (int j = 0; j < 4; ++j) {
      r0[j] = (short)f2bfs(a0[j]); r0[4 + j] = (short)f2bfs(a1[j]);
      r1[j] = (short)f2bfs(a2[j]); r1[4 + j] = (short)f2bfs(a3[j]);
    }
    int ch = dd0 >> 3;
    *(bf16x8*)&tb[kk * 64 + ((ch ^ swz2(kk)) << 3)] = r0;
    *(bf16x8*)&tb[kk * 64 + (((ch + 1) ^ swz2(kk)) << 3)] = r1;
  }
  __syncthreads();
  {
    const int dv = tid >> 2, ks = (tid & 3) * 16;
    bf16x8 w0, w1;
    #pragma unroll
    for (int j = 0; j < 8; ++j) {
      int r0 = ks + j, r1 = ks + 8 + j;
      w0[j] = (short)tb[r0 * 64 + (((dv >> 3) ^ swz2(r0)) << 3) + (dv & 7)];
      w1[j] = (short)tb[r1 * 64 + (((dv >> 3) ^ swz2(r1)) << 3) + (dv & 7)];
    }
    unsigned short* dst = vt + ((long)(b * DV + dv0 + dv)) * LK + k0 + ks;
    *(bf16x8*)dst = w0;
    *(bf16x8*)(dst + 8) = w1;
  }
}

// ---------- main: flash attention, 32 q-rows/wave (2x register blocking) ----------
__global__ __launch_bounds__(256, 2) void attn_fwd3(
    const float* __restrict__ qp, const unsigned short* __restrict__ wsK,
    const unsigned short* __restrict__ wsVt, float* __restrict__ op) {
  // LDS: 2 x (K[64][128] + Vt[128][64]) bf16 = 64 KB, 16B-chunk swizzled
  __shared__ __align__(16) unsigned short sm[32768];

  const int tid = threadIdx.x;
  const int wid = tid >> 6;
  const int lane = tid & 63;
  const int g = lane >> 4;
  const int c = lane & 15;

  // 256 blocks; 32 consecutive blocks (2 batches) per XCD
  const int bid = blockIdx.x;
  const int sbid = (bid & 7) * 32 + (bid >> 3);
  const int b = sbid >> 4;
  const int qb = (sbid & 15) * 128;
  const int qwave = qb + wid * 32;    // this wave's 32 q-rows

  // Q fragments (B-operand), two 16-row groups h=0,1; scale*log2e folded
  bf16x8 aq[2][4];
  #pragma unroll
  for (int h = 0; h < 2; ++h) {
    const float* qrow = qp + ((long)(b * LQ + qwave + h * 16 + c)) * D;
    #pragma unroll
    for (int ks = 0; ks < 4; ++ks) {
      f32x4 x0 = *(const f32x4*)(qrow + ks * 32 + g * 8);
      f32x4 x1 = *(const f32x4*)(qrow + ks * 32 + g * 8 + 4);
      #pragma unroll
      for (int j = 0; j < 4; ++j) {
        aq[h][ks][j]     = (short)f2bfs(x0[j] * QSCALE);
        aq[h][ks][4 + j] = (short)f2bfs(x1[j] * QSCALE);
      }
    }
  }

  const unsigned short* kbatch = wsK + (long)b * LK * D;
  const unsigned short* vbatch = wsVt + (long)b * DV * LK;

  auto stage = [&](int buf, int kv0) {
    const unsigned short* ksrc = kbatch + (long)kv0 * D;
    #pragma unroll
    for (int it = 0; it < 4; ++it) {
      int ci = it * 256 + tid, row = ci >> 4, c16 = ci & 15;
      gload16(ksrc + row * D + ((c16 ^ swz2(row)) << 3), &sm[buf * 16384 + ci * 8]);
    }
    #pragma unroll
    for (int it = 0; it < 4; ++it) {
      int ci = it * 256 + tid, row = ci >> 3, c8 = ci & 7;
      gload16(vbatch + (long)row * LK + kv0 + ((c8 ^ swz2(row)) << 3),
              &sm[buf * 16384 + 8192 + ci * 8]);
    }
  };

  stage(0, 0);
  __syncthreads();

  f32x4 o[2][8];
  f32x4 fz = {0.f, 0.f, 0.f, 0.f};
  #pragma unroll
  for (int h = 0; h < 2; ++h)
    #pragma unroll
    for (int i = 0; i < 8; ++i) o[h][i] = fz;
  float m_s[2] = {-1e30f, -1e30f};
  float l_s[2] = {0.f, 0.f};

  for (int t = 0; t < NT; ++t) {
    const int cur = t & 1;
    if (t + 1 < NT) stage(cur ^ 1, (t + 1) * KVBLK);
    const int kb = cur * 16384, vb = kb + 8192;

    // ---- S^T = K Q^T, k-row permutation; lane (g,c) holds, for group h,
    //      P[q=c][k = 8g + r + 4*(tt&1) + 32*(tt>>1)] in s[h][tt][r]
    f32x4 s[2][4];
    #pragma unroll
    for (int h = 0; h < 2; ++h)
      #pragma unroll
      for (int i = 0; i < 4; ++i) s[h][i] = fz;
    __builtin_amdgcn_s_setprio(1);
    #pragma unroll
    for (int tt = 0; tt < 4; ++tt) {
      int row = 32 * (tt >> 1) + 4 * (tt & 1) + (c & 3) + ((c >> 2) << 3);
      int sz = swz2(row);
      #pragma unroll
      for (int ks = 0; ks < 4; ++ks) {
        bf16x8 ak = *(const bf16x8*)&sm[kb + row * 128 + ((((ks << 2) + g) ^ sz) << 3)];
        s[0][tt] = __builtin_amdgcn_mfma_f32_16x16x32_bf16(ak, aq[0][ks], s[0][tt], 0, 0, 0);
        s[1][tt] = __builtin_amdgcn_mfma_f32_16x16x32_bf16(ak, aq[1][ks], s[1][tt], 0, 0, 0);
      }
    }
    __builtin_amdgcn_s_setprio(0);

    // ---- online softmax (log2 domain), per q-group h
    bf16x8 pa[2][2];
    #pragma unroll
    for (int h = 0; h < 2; ++h) {
      float pm = s[h][0][0];
      #pragma unroll
      for (int tt = 0; tt < 4; ++tt)
        #pragma unroll
        for (int r = 0; r < 4; ++r) pm = fmaxf(pm, s[h][tt][r]);
      pm = fmaxf(pm, __shfl_xor(pm, 16));
      pm = fmaxf(pm, __shfl_xor(pm, 32));
      if (!__all(pm <= m_s[h] + 8.0f)) {       // defer-max (T13)
        float mn = fmaxf(m_s[h], pm);
        float al = exp2f(m_s[h] - mn);
        l_s[h] *= al;
        float al4[4];
        #pragma unroll
        for (int r = 0; r < 4; ++r) al4[r] = __shfl(al, 4 * g + r);
        #pragma unroll
        for (int dvt = 0; dvt < 8; ++dvt)
          #pragma unroll
          for (int r = 0; r < 4; ++r) o[h][dvt][r] *= al4[r];
        m_s[h] = mn;
      }
      float sum = 0.f;
      #pragma unroll
      for (int tt = 0; tt < 4; ++tt)
        #pragma unroll
        for (int r = 0; r < 4; ++r) {
          float p = exp2f(s[h][tt][r] - m_s[h]);
          s[h][tt][r] = p;
          sum += p;
        }
      sum += __shfl_xor(sum, 16);
      sum += __shfl_xor(sum, 32);
      l_s[h] += sum;

      // P already lane-local in A-fragment layout: pack to bf16
      #pragma unroll
      for (int ks = 0; ks < 2; ++ks) {
        #pragma unroll
        for (int j = 0; j < 4; ++j) {
          pa[h][ks][j]     = (short)f2bfs(s[h][2 * ks][j]);
          pa[h][ks][4 + j] = (short)f2bfs(s[h][2 * ks + 1][j]);
        }
      }
    }

    // ---- O += P V (each V-fragment read feeds both q-groups)
    __builtin_amdgcn_s_setprio(1);
    #pragma unroll
    for (int ks = 0; ks < 2; ++ks) {
      #pragma unroll
      for (int dvt = 0; dvt < 8; ++dvt) {
        int row = dvt * 16 + c;
        bf16x8 vbf = *(const bf16x8*)&sm[vb + row * 64 + ((((ks << 2) + g) ^ swz2(row)) << 3)];
        o[0][dvt] = __builtin_amdgcn_mfma_f32_16x16x32_bf16(pa[0][ks], vbf, o[0][dvt], 0, 0, 0);
        o[1][dvt] = __builtin_amdgcn_mfma_f32_16x16x32_bf16(pa[1][ks], vbf, o[1][dvt], 0, 0, 0);
      }
    }
    __builtin_amdgcn_s_setprio(0);

    __syncthreads();
  }

  // ---- epilogue: O / l ; o[h][dvt][r] is O[q=h*16+4g+r][dv=16dvt+c]
  #pragma unroll
  for (int h = 0; h < 2; ++h) {
    float linv[4];
    #pragma unroll
    for (int r = 0; r < 4; ++r) linv[r] = 1.f / __shfl(l_s[h], 4 * g + r);
    float* dst = op + ((long)(b * LQ + qwave + h * 16)) * DV;
    #pragma unroll
    for (int r = 0; r < 4; ++r)
      #pragma unroll
      for (int dvt = 0; dvt < 8; ++dvt)
        dst[(4 * g + r) * DV + dvt * 16 + c] = o[h][dvt][r] * linv[r];
  }
}

// ---------- legacy fallback (no-workspace path) ----------
__device__ __forceinline__ int swzc(int row, int c16) {
  return c16 ^ ((row ^ (row >> 3)) & 7);
}

__global__ __launch_bounds__(256, 2) void attn_fwd(
    const float* __restrict__ qp, const float* __restrict__ kp,
    const float* __restrict__ vp, float* __restrict__ op) {
  __shared__ __align__(16) unsigned short smm[28672];
  const int tid = threadIdx.x, wid = tid >> 6, lane = tid & 63;
  const int g = lane >> 4, c = lane & 15;
  const int b = blockIdx.y, qb = blockIdx.x * 64;
  const float* qg = qp + ((long)b * LQ + qb) * D;
  const float* kg = kp + (long)b * LK * D;
  const float* vg = vp + (long)b * LK * DV;
  #pragma unroll
  for (int it = 0; it < 4; ++it) {
    int ch = it * 256 + tid, row = ch >> 4, c16 = ch & 15;
    const float* src = qg + row * D + c16 * 8;
    f32x4 f0 = *(const f32x4*)(src);
    f32x4 f1 = *(const f32x4*)(src + 4);
    bf16x8 fr;
    #pragma unroll
    for (int j = 0; j < 4; ++j) {
      fr[j] = (short)f2bf(f0[j] * SCALE);
      fr[4 + j] = (short)f2bf(f1[j] * SCALE);
    }
    *(bf16x8*)&smm[row * 128 + swzc(row, c16) * 8] = fr;
  }
  __syncthreads();
  bf16x8 aq[4];
  #pragma unroll
  for (int ks = 0; ks < 4; ++ks) {
    int row = wid * 16 + c;
    aq[ks] = *(const bf16x8*)&smm[row * 128 + swzc(row, ks * 4 + g) * 8];
  }
  f32x4 o[8]; f32x4 fz = {0.f, 0.f, 0.f, 0.f};
  #pragma unroll
  for (int i = 0; i < 8; ++i) o[i] = fz;
  float m_r[4] = {-1e30f, -1e30f, -1e30f, -1e30f};
  float l_r[4] = {0.f, 0.f, 0.f, 0.f};
  const int pbase = 24576 + wid * 1024;
  for (int kv0 = 0; kv0 < LK; kv0 += KVBLK) {
    __syncthreads();
    const float* ksrc = kg + (long)kv0 * D;
    #pragma unroll
    for (int it = 0; it < 4; ++it) {
      int ch = it * 256 + tid, row = ch >> 4, c16 = ch & 15;
      const float* src = ksrc + row * D + c16 * 8;
      f32x4 f0 = *(const f32x4*)(src);
      f32x4 f1 = *(const f32x4*)(src + 4);
      bf16x8 fr;
      #pragma unroll
      for (int j = 0; j < 4; ++j) { fr[j] = (short)f2bf(f0[j]); fr[4 + j] = (short)f2bf(f1[j]); }
      *(bf16x8*)&smm[8192 + row * 128 + swzc(row, c16) * 8] = fr;
    }
    {
      const float* vsrc = vg + (long)kv0 * DV;
      int dvq = (tid & 31) * 4, kg8 = tid >> 5;
      f32x4 col[8];
      #pragma unroll
      for (int j = 0; j < 8; ++j) col[j] = *(const f32x4*)(vsrc + (kg8 * 8 + j) * DV + dvq);
      #pragma unroll
      for (int i = 0; i < 4; ++i) {
        int dv = dvq + i;
        bf16x8 fr;
        #pragma unroll
        for (int j = 0; j < 8; ++j) fr[j] = (short)f2bf(col[j][i]);
        *(bf16x8*)&smm[16384 + dv * 64 + swzc(dv, kg8) * 8] = fr;
      }
    }
    __syncthreads();
    f32x4 s[4];
    #pragma unroll
    for (int i = 0; i < 4; ++i) s[i] = fz;
    #pragma unroll
    for (int ks = 0; ks < 4; ++ks) {
      #pragma unroll
      for (int t = 0; t < 4; ++t) {
        int row = t * 16 + c;
        bf16x8 bk = *(const bf16x8*)&smm[8192 + row * 128 + swzc(row, ks * 4 + g) * 8];
        s[t] = __builtin_amdgcn_mfma_f32_16x16x32_bf16(aq[ks], bk, s[t], 0, 0, 0);
      }
    }
    #pragma unroll
    for (int r = 0; r < 4; ++r) {
      float pm = fmaxf(fmaxf(s[0][r], s[1][r]), fmaxf(s[2][r], s[3][r]));
      pm = fmaxf(pm, __shfl_xor(pm, 1));
      pm = fmaxf(pm, __shfl_xor(pm, 2));
      pm = fmaxf(pm, __shfl_xor(pm, 4));
      pm = fmaxf(pm, __shfl_xor(pm, 8));
      float mn = fmaxf(m_r[r], pm);
      float al = exp2f((m_r[r] - mn) * LOG2E);
      float sum = 0.f;
      #pragma unroll
      for (int t = 0; t < 4; ++t) {
        float p = exp2f((s[t][r] - mn) * LOG2E);
        s[t][r] = p; sum += p;
      }
      sum += __shfl_xor(sum, 1); sum += __shfl_xor(sum, 2);
      sum += __shfl_xor(sum, 4); sum += __shfl_xor(sum, 8);
      l_r[r] = l_r[r] * al + sum; m_r[r] = mn;
      #pragma unroll
      for (int dvt = 0; dvt < 8; ++dvt) o[dvt][r] *= al;
    }
    #pragma unroll
    for (int t = 0; t < 4; ++t)
      #pragma unroll
      for (int r = 0; r < 4; ++r) {
        int row = g * 4 + r, colx = c + 16 * t;
        smm[pbase + row * 64 + swzc(row, colx >> 3) * 8 + (colx & 7)] = f2bf(s[t][r]);
      }
    #pragma unroll
    for (int ks = 0; ks < 2; ++ks) {
      bf16x8 pa = *(const bf16x8*)&smm[pbase + c * 64 + swzc(c, ks * 4 + g) * 8];
      #pragma unroll
      for (int dvt = 0; dvt < 8; ++dvt) {
        int row = dvt * 16 + c;
        bf16x8 vb2 = *(const bf16x8*)&smm[16384 + row * 64 + swzc(row, ks * 4 + g) * 8];
        o[dvt] = __builtin_amdgcn_mfma_f32_16x16x32_bf16(pa, vb2, o[dvt], 0, 0, 0);
      }
    }
  }
  float* dst = op + ((long)b * LQ + qb + wid * 16) * DV;
  #pragma unroll
  for (int r = 0; r < 4; ++r) {
    float inv = 1.f / l_r[r];
    #pragma unroll
    for (int dvt = 0; dvt < 8; ++dvt)
      dst[(g * 4 + r) * DV + dvt * 16 + c] = o[dvt][r] * inv;
  }
}

extern "C" void kernel_launch(void* const* d_in, const int* in_sizes, int n_in,
                              void* d_out, int out_size, void* d_ws, size_t ws_size,
                              hipStream_t stream) {
  const float* q = (const float*)d_in[0];
  const float* k = (const float*)d_in[1];
  const float* v = (const float*)d_in[2];
  float* out = (float*)d_out;

  const size_t kelems = (size_t)NB * LK * D;
  const size_t need = kelems * 2 * 2;                 // K + Vt, bf16
  if (ws_size >= need) {
    unsigned short* wsK = (unsigned short*)d_ws;
    unsigned short* wsVt = wsK + kelems;
    conv_bf16<<<dim3((int)(kelems / 8 / 256)), dim3(256), 0, stream>>>(k, wsK, 1.0f);
    conv_vt<<<dim3(LK / 64, DV / 64, NB), dim3(256), 0, stream>>>(v, wsVt);
    attn_fwd3<<<dim3(NB * LQ / 128), dim3(256), 0, stream>>>(q, wsK, wsVt, out);
  } else {
    attn_fwd<<<dim3(LQ / 64, NB), dim3(256), 0, stream>>>(q, k, v, out);
  }
}

// Round 4
// 76.983 us; speedup vs baseline: 1.1648x; 1.1648x over previous
//
#include <hip/hip_runtime.h>
#include <hip/hip_bf16.h>

typedef float f32x4 __attribute__((ext_vector_type(4)));
typedef short bf16x8 __attribute__((ext_vector_type(8)));

constexpr int NB = 16, LQ = 2048, LK = 2048, D = 128, DV = 128;
constexpr int KVBLK = 64;
constexpr int NTH = 16;                         // 1024 keys per half / 64
constexpr float SCALE = 0.08838834764831843f;   // 1/sqrt(128)
constexpr float LOG2E = 1.4426950408889634f;
constexpr float QSCALE = SCALE * LOG2E;         // softmax in log2 domain

// ---------- helpers ----------
__device__ __forceinline__ unsigned short f2bfs(float f) {
  __hip_bfloat16 h = __float2bfloat16(f);      // RNE
  return __builtin_bit_cast(unsigned short, h);
}

__device__ __forceinline__ unsigned short f2bf(float f) {
  unsigned int u = __float_as_uint(f);
  u += 0x7FFFu + ((u >> 16) & 1u);
  return (unsigned short)(u >> 16);
}

__device__ __forceinline__ int swz2(int row) {
  return (row ^ (row >> 1) ^ (row >> 3)) & 7;
}

typedef const __attribute__((address_space(1))) void* gas1_t;
typedef __attribute__((address_space(3))) void* las3_t;
__device__ __forceinline__ void gload16(const void* g, void* l) {
  __builtin_amdgcn_global_load_lds((gas1_t)g, (las3_t)l, 16, 0, 0);
}

// ---------- prepass: fp32 -> bf16 ----------
__global__ __launch_bounds__(256) void conv_bf16(const float* __restrict__ in,
                                                 unsigned short* __restrict__ out,
                                                 float scale) {
  int i = blockIdx.x * 256 + threadIdx.x;
  f32x4 a = ((const f32x4*)in)[2 * i];
  f32x4 b = ((const f32x4*)in)[2 * i + 1];
  bf16x8 r;
  #pragma unroll
  for (int j = 0; j < 4; ++j) {
    r[j]     = (short)f2bfs(a[j] * scale);
    r[4 + j] = (short)f2bfs(b[j] * scale);
  }
  ((bf16x8*)out)[i] = r;
}

// ---------- prepass: V[b][k][dv] fp32 -> Vt[b][dv][k] bf16 ----------
__global__ __launch_bounds__(256) void conv_vt(const float* __restrict__ v,
                                               unsigned short* __restrict__ vt) {
  __shared__ __align__(16) unsigned short tb[64 * 64];
  const int tid = threadIdx.x;
  const int k0 = blockIdx.x * 64, dv0 = blockIdx.y * 64, b = blockIdx.z;
  {
    const int kk = tid >> 2, dd0 = (tid & 3) * 16;
    const float* src = v + ((long)(b * LK + k0 + kk)) * DV + dv0 + dd0;
    f32x4 a0 = ((const f32x4*)src)[0];
    f32x4 a1 = ((const f32x4*)src)[1];
    f32x4 a2 = ((const f32x4*)src)[2];
    f32x4 a3 = ((const f32x4*)src)[3];
    bf16x8 r0, r1;
    #pragma unroll
    for (int j = 0; j < 4; ++j) {
      r0[j] = (short)f2bfs(a0[j]); r0[4 + j] = (short)f2bfs(a1[j]);
      r1[j] = (short)f2bfs(a2[j]); r1[4 + j] = (short)f2bfs(a3[j]);
    }
    int ch = dd0 >> 3;
    *(bf16x8*)&tb[kk * 64 + ((ch ^ swz2(kk)) << 3)] = r0;
    *(bf16x8*)&tb[kk * 64 + (((ch + 1) ^ swz2(kk)) << 3)] = r1;
  }
  __syncthreads();
  {
    const int dv = tid >> 2, ks = (tid & 3) * 16;
    bf16x8 w0, w1;
    #pragma unroll
    for (int j = 0; j < 8; ++j) {
      int r0 = ks + j, r1 = ks + 8 + j;
      w0[j] = (short)tb[r0 * 64 + (((dv >> 3) ^ swz2(r0)) << 3) + (dv & 7)];
      w1[j] = (short)tb[r1 * 64 + (((dv >> 3) ^ swz2(r1)) << 3) + (dv & 7)];
    }
    unsigned short* dst = vt + ((long)(b * DV + dv0 + dv)) * LK + k0 + ks;
    *(bf16x8*)dst = w0;
    *(bf16x8*)(dst + 8) = w1;
  }
}

// ---------- main: 8-wave block, in-block split-KV, counted-vmcnt pipeline ----
__global__ __launch_bounds__(512, 2) void attn_fwd4(
    const float* __restrict__ qp, const unsigned short* __restrict__ wsK,
    const unsigned short* __restrict__ wsVt, float* __restrict__ op) {
  // LDS 128 KB: per (half, buf): K[64][128] @ +0, Vt[128][64] @ +8192 (uint16)
  __shared__ __align__(16) unsigned short sm[65536];

  const int tid = threadIdx.x;
  const int wid = tid >> 6;        // 0..7
  const int h2  = wid >> 2;        // KV half (0: keys 0..1023, 1: 1024..2047)
  const int lane = tid & 63;
  const int g = lane >> 4;
  const int c = lane & 15;
  const int ht = tid & 255;        // thread id within half-group

  // 256 blocks; 32 consecutive per XCD
  const int bid = blockIdx.x;
  const int sbid = (bid & 7) * 32 + (bid >> 3);
  const int b = sbid >> 4;
  const int qb = (sbid & 15) * 128;
  const int qwave = qb + (wid & 3) * 32;   // this wave's 32 q-rows

  // ---- Q fragments (B-operand), 2 groups of 16 rows; scale*log2e folded ----
  bf16x8 aq[2][4];
  #pragma unroll
  for (int h = 0; h < 2; ++h) {
    const float* qrow = qp + ((long)(b * LQ + qwave + h * 16 + c)) * D;
    #pragma unroll
    for (int ks = 0; ks < 4; ++ks) {
      f32x4 x0 = *(const f32x4*)(qrow + ks * 32 + g * 8);
      f32x4 x1 = *(const f32x4*)(qrow + ks * 32 + g * 8 + 4);
      #pragma unroll
      for (int j = 0; j < 4; ++j) {
        aq[h][ks][j]     = (short)f2bfs(x0[j] * QSCALE);
        aq[h][ks][4 + j] = (short)f2bfs(x1[j] * QSCALE);
      }
    }
  }
  __builtin_amdgcn_sched_barrier(0);   // Q loads fully consumed before staging

  const unsigned short* kbatch = wsK + (long)b * LK * D;
  const unsigned short* vbatch = wsVt + (long)b * DV * LK;
  const int kvbase = h2 * 1024;
  const int lbase = h2 * 32768;

  // stage one KV tile (this half's group of 256 threads; 8 gload16/thread)
  auto stage = [&](int buf, int tt) {
    const int kv0 = kvbase + tt * KVBLK;
    const unsigned short* ksrc = kbatch + (long)kv0 * D;
    const int base = lbase + buf * 16384;
    #pragma unroll
    for (int it = 0; it < 4; ++it) {
      int ci = it * 256 + ht, row = ci >> 4, c16 = ci & 15;
      gload16(ksrc + row * D + ((c16 ^ swz2(row)) << 3), &sm[base + ci * 8]);
    }
    #pragma unroll
    for (int it = 0; it < 4; ++it) {
      int ci = it * 256 + ht, row = ci >> 3, c8 = ci & 7;
      gload16(vbatch + (long)row * LK + kv0 + ((c8 ^ swz2(row)) << 3),
              &sm[base + 8192 + ci * 8]);
    }
  };

  stage(0, 0);
  stage(1, 1);

  f32x4 o[2][8];
  f32x4 fz = {0.f, 0.f, 0.f, 0.f};
  #pragma unroll
  for (int h = 0; h < 2; ++h)
    #pragma unroll
    for (int i = 0; i < 8; ++i) o[h][i] = fz;
  float m_s[2] = {-1e30f, -1e30f};
  float l_s[2] = {0.f, 0.f};

  for (int t = 0; t < NTH; ++t) {
    // wait for stage(t); keep stage(t+1) in flight (counted vmcnt, T4)
    if (t < NTH - 1) {
      asm volatile("s_waitcnt vmcnt(8)" ::: "memory");
    } else {
      asm volatile("s_waitcnt vmcnt(0)" ::: "memory");
    }
    __builtin_amdgcn_sched_barrier(0);
    __builtin_amdgcn_s_barrier();          // all waves' stage(t) visible
    __builtin_amdgcn_sched_barrier(0);

    const int cur = t & 1;
    const int kb = lbase + cur * 16384, vb = kb + 8192;

    // ---- S^T = K Q^T; lane (g,c) holds P[q=c][k=8g+r+4(tt&1)+32(tt>>1)]
    f32x4 s[2][4];
    #pragma unroll
    for (int h = 0; h < 2; ++h)
      #pragma unroll
      for (int i = 0; i < 4; ++i) s[h][i] = fz;
    __builtin_amdgcn_s_setprio(1);
    #pragma unroll
    for (int tt = 0; tt < 4; ++tt) {
      int row = 32 * (tt >> 1) + 4 * (tt & 1) + (c & 3) + ((c >> 2) << 3);
      int sz = swz2(row);
      #pragma unroll
      for (int ks = 0; ks < 4; ++ks) {
        bf16x8 ak = *(const bf16x8*)&sm[kb + row * 128 + ((((ks << 2) + g) ^ sz) << 3)];
        s[0][tt] = __builtin_amdgcn_mfma_f32_16x16x32_bf16(ak, aq[0][ks], s[0][tt], 0, 0, 0);
        s[1][tt] = __builtin_amdgcn_mfma_f32_16x16x32_bf16(ak, aq[1][ks], s[1][tt], 0, 0, 0);
      }
    }
    __builtin_amdgcn_s_setprio(0);

    // ---- online softmax (log2 domain), per q-group h
    bf16x8 pa[2][2];
    #pragma unroll
    for (int h = 0; h < 2; ++h) {
      float pm = s[h][0][0];
      #pragma unroll
      for (int tt = 0; tt < 4; ++tt)
        #pragma unroll
        for (int r = 0; r < 4; ++r) pm = fmaxf(pm, s[h][tt][r]);
      pm = fmaxf(pm, __shfl_xor(pm, 16));
      pm = fmaxf(pm, __shfl_xor(pm, 32));
      if (!__all(pm <= m_s[h] + 8.0f)) {     // defer-max (T13)
        float mn = fmaxf(m_s[h], pm);
        float al = exp2f(m_s[h] - mn);
        l_s[h] *= al;
        float al4[4];
        #pragma unroll
        for (int r = 0; r < 4; ++r) al4[r] = __shfl(al, 4 * g + r);
        #pragma unroll
        for (int dvt = 0; dvt < 8; ++dvt)
          #pragma unroll
          for (int r = 0; r < 4; ++r) o[h][dvt][r] *= al4[r];
        m_s[h] = mn;
      }
      float sum = 0.f;
      #pragma unroll
      for (int tt = 0; tt < 4; ++tt)
        #pragma unroll
        for (int r = 0; r < 4; ++r) {
          float p = exp2f(s[h][tt][r] - m_s[h]);
          s[h][tt][r] = p;
          sum += p;
        }
      sum += __shfl_xor(sum, 16);
      sum += __shfl_xor(sum, 32);
      l_s[h] += sum;

      #pragma unroll
      for (int ks = 0; ks < 2; ++ks) {
        #pragma unroll
        for (int j = 0; j < 4; ++j) {
          pa[h][ks][j]     = (short)f2bfs(s[h][2 * ks][j]);
          pa[h][ks][4 + j] = (short)f2bfs(s[h][2 * ks + 1][j]);
        }
      }
    }

    // ---- O += P V (each V read feeds both q-groups)
    __builtin_amdgcn_s_setprio(1);
    #pragma unroll
    for (int ks = 0; ks < 2; ++ks) {
      #pragma unroll
      for (int dvt = 0; dvt < 8; ++dvt) {
        int row = dvt * 16 + c;
        bf16x8 vbf = *(const bf16x8*)&sm[vb + row * 64 + ((((ks << 2) + g) ^ swz2(row)) << 3)];
        o[0][dvt] = __builtin_amdgcn_mfma_f32_16x16x32_bf16(pa[0][ks], vbf, o[0][dvt], 0, 0, 0);
        o[1][dvt] = __builtin_amdgcn_mfma_f32_16x16x32_bf16(pa[1][ks], vbf, o[1][dvt], 0, 0, 0);
      }
    }
    __builtin_amdgcn_s_setprio(0);

    __builtin_amdgcn_sched_barrier(0);
    __builtin_amdgcn_s_barrier();          // all waves done reading buf[cur]
    __builtin_amdgcn_sched_barrier(0);

    if (t < NTH - 2) stage(cur, t + 2);    // refill just-freed buffer
  }

  // ---- in-LDS combine of the two KV halves ----
  float* scrf = (float*)sm;                // all 128 KB free now
  if (wid >= 4) {
    float* scr = scrf + (size_t)(wid & 3) * 8192;
    #pragma unroll
    for (int h = 0; h < 2; ++h) {
      #pragma unroll
      for (int r = 0; r < 4; ++r) {
        int ql = h * 16 + 4 * g + r;
        #pragma unroll
        for (int dvt = 0; dvt < 8; ++dvt)
          scr[ql * 128 + dvt * 16 + c] = o[h][dvt][r];
      }
      if (g == 0) {
        scr[4096 + h * 16 + c] = m_s[h];
        scr[4160 + h * 16 + c] = l_s[h];
      }
    }
  }
  __syncthreads();
  if (wid < 4) {
    const float* scr = scrf + (size_t)wid * 8192;
    #pragma unroll
    for (int h = 0; h < 2; ++h) {
      #pragma unroll
      for (int r = 0; r < 4; ++r) {
        int q = 4 * g + r;
        int ql = h * 16 + q;
        float m0 = __shfl(m_s[h], q);
        float l0 = __shfl(l_s[h], q);
        float m1 = scr[4096 + ql];
        float l1 = scr[4160 + ql];
        float mm = fmaxf(m0, m1);
        float a0 = exp2f(m0 - mm), a1 = exp2f(m1 - mm);
        float inv = 1.f / (a0 * l0 + a1 * l1);
        float* dst = op + ((long)(b * LQ + qwave + ql)) * DV;
        #pragma unroll
        for (int dvt = 0; dvt < 8; ++dvt)
          dst[dvt * 16 + c] = (a0 * o[h][dvt][r] + a1 * scr[ql * 128 + dvt * 16 + c]) * inv;
      }
    }
  }
}

// ---------- legacy fallback (no-workspace path) ----------
__device__ __forceinline__ int swzc(int row, int c16) {
  return c16 ^ ((row ^ (row >> 3)) & 7);
}

__global__ __launch_bounds__(256, 2) void attn_fwd(
    const float* __restrict__ qp, const float* __restrict__ kp,
    const float* __restrict__ vp, float* __restrict__ op) {
  __shared__ __align__(16) unsigned short smm[28672];
  const int tid = threadIdx.x, wid = tid >> 6, lane = tid & 63;
  const int g = lane >> 4, c = lane & 15;
  const int b = blockIdx.y, qb = blockIdx.x * 64;
  const float* qg = qp + ((long)b * LQ + qb) * D;
  const float* kg = kp + (long)b * LK * D;
  const float* vg = vp + (long)b * LK * DV;
  #pragma unroll
  for (int it = 0; it < 4; ++it) {
    int ch = it * 256 + tid, row = ch >> 4, c16 = ch & 15;
    const float* src = qg + row * D + c16 * 8;
    f32x4 f0 = *(const f32x4*)(src);
    f32x4 f1 = *(const f32x4*)(src + 4);
    bf16x8 fr;
    #pragma unroll
    for (int j = 0; j < 4; ++j) {
      fr[j] = (short)f2bf(f0[j] * SCALE);
      fr[4 + j] = (short)f2bf(f1[j] * SCALE);
    }
    *(bf16x8*)&smm[row * 128 + swzc(row, c16) * 8] = fr;
  }
  __syncthreads();
  bf16x8 aq[4];
  #pragma unroll
  for (int ks = 0; ks < 4; ++ks) {
    int row = wid * 16 + c;
    aq[ks] = *(const bf16x8*)&smm[row * 128 + swzc(row, ks * 4 + g) * 8];
  }
  f32x4 o[8]; f32x4 fz = {0.f, 0.f, 0.f, 0.f};
  #pragma unroll
  for (int i = 0; i < 8; ++i) o[i] = fz;
  float m_r[4] = {-1e30f, -1e30f, -1e30f, -1e30f};
  float l_r[4] = {0.f, 0.f, 0.f, 0.f};
  const int pbase = 24576 + wid * 1024;
  for (int kv0 = 0; kv0 < LK; kv0 += KVBLK) {
    __syncthreads();
    const float* ksrc = kg + (long)kv0 * D;
    #pragma unroll
    for (int it = 0; it < 4; ++it) {
      int ch = it * 256 + tid, row = ch >> 4, c16 = ch & 15;
      const float* src = ksrc + row * D + c16 * 8;
      f32x4 f0 = *(const f32x4*)(src);
      f32x4 f1 = *(const f32x4*)(src + 4);
      bf16x8 fr;
      #pragma unroll
      for (int j = 0; j < 4; ++j) { fr[j] = (short)f2bf(f0[j]); fr[4 + j] = (short)f2bf(f1[j]); }
      *(bf16x8*)&smm[8192 + row * 128 + swzc(row, c16) * 8] = fr;
    }
    {
      const float* vsrc = vg + (long)kv0 * DV;
      int dvq = (tid & 31) * 4, kg8 = tid >> 5;
      f32x4 col[8];
      #pragma unroll
      for (int j = 0; j < 8; ++j) col[j] = *(const f32x4*)(vsrc + (kg8 * 8 + j) * DV + dvq);
      #pragma unroll
      for (int i = 0; i < 4; ++i) {
        int dv = dvq + i;
        bf16x8 fr;
        #pragma unroll
        for (int j = 0; j < 8; ++j) fr[j] = (short)f2bf(col[j][i]);
        *(bf16x8*)&smm[16384 + dv * 64 + swzc(dv, kg8) * 8] = fr;
      }
    }
    __syncthreads();
    f32x4 s[4];
    #pragma unroll
    for (int i = 0; i < 4; ++i) s[i] = fz;
    #pragma unroll
    for (int ks = 0; ks < 4; ++ks) {
      #pragma unroll
      for (int t = 0; t < 4; ++t) {
        int row = t * 16 + c;
        bf16x8 bk = *(const bf16x8*)&smm[8192 + row * 128 + swzc(row, ks * 4 + g) * 8];
        s[t] = __builtin_amdgcn_mfma_f32_16x16x32_bf16(aq[ks], bk, s[t], 0, 0, 0);
      }
    }
    #pragma unroll
    for (int r = 0; r < 4; ++r) {
      float pm = fmaxf(fmaxf(s[0][r], s[1][r]), fmaxf(s[2][r], s[3][r]));
      pm = fmaxf(pm, __shfl_xor(pm, 1));
      pm = fmaxf(pm, __shfl_xor(pm, 2));
      pm = fmaxf(pm, __shfl_xor(pm, 4));
      pm = fmaxf(pm, __shfl_xor(pm, 8));
      float mn = fmaxf(m_r[r], pm);
      float al = exp2f((m_r[r] - mn) * LOG2E);
      float sum = 0.f;
      #pragma unroll
      for (int t = 0; t < 4; ++t) {
        float p = exp2f((s[t][r] - mn) * LOG2E);
        s[t][r] = p; sum += p;
      }
      sum += __shfl_xor(sum, 1); sum += __shfl_xor(sum, 2);
      sum += __shfl_xor(sum, 4); sum += __shfl_xor(sum, 8);
      l_r[r] = l_r[r] * al + sum; m_r[r] = mn;
      #pragma unroll
      for (int dvt = 0; dvt < 8; ++dvt) o[dvt][r] *= al;
    }
    #pragma unroll
    for (int t = 0; t < 4; ++t)
      #pragma unroll
      for (int r = 0; r < 4; ++r) {
        int row = g * 4 + r, colx = c + 16 * t;
        smm[pbase + row * 64 + swzc(row, colx >> 3) * 8 + (colx & 7)] = f2bf(s[t][r]);
      }
    #pragma unroll
    for (int ks = 0; ks < 2; ++ks) {
      bf16x8 pa = *(const bf16x8*)&smm[pbase + c * 64 + swzc(c, ks * 4 + g) * 8];
      #pragma unroll
      for (int dvt = 0; dvt < 8; ++dvt) {
        int row = dvt * 16 + c;
        bf16x8 vb2 = *(const bf16x8*)&smm[16384 + row * 64 + swzc(row, ks * 4 + g) * 8];
        o[dvt] = __builtin_amdgcn_mfma_f32_16x16x32_bf16(pa, vb2, o[dvt], 0, 0, 0);
      }
    }
  }
  float* dst = op + ((long)b * LQ + qb + wid * 16) * DV;
  #pragma unroll
  for (int r = 0; r < 4; ++r) {
    float inv = 1.f / l_r[r];
    #pragma unroll
    for (int dvt = 0; dvt < 8; ++dvt)
      dst[(g * 4 + r) * DV + dvt * 16 + c] = o[dvt][r] * inv;
  }
}

extern "C" void kernel_launch(void* const* d_in, const int* in_sizes, int n_in,
                              void* d_out, int out_size, void* d_ws, size_t ws_size,
                              hipStream_t stream) {
  const float* q = (const float*)d_in[0];
  const float* k = (const float*)d_in[1];
  const float* v = (const float*)d_in[2];
  float* out = (float*)d_out;

  const size_t kelems = (size_t)NB * LK * D;
  const size_t need = kelems * 2 * 2;                 // K + Vt, bf16
  if (ws_size >= need) {
    unsigned short* wsK = (unsigned short*)d_ws;
    unsigned short* wsVt = wsK + kelems;
    conv_bf16<<<dim3((int)(kelems / 8 / 256)), dim3(256), 0, stream>>>(k, wsK, 1.0f);
    conv_vt<<<dim3(LK / 64, DV / 64, NB), dim3(256), 0, stream>>>(v, wsVt);
    attn_fwd4<<<dim3(NB * LQ / 128), dim3(512), 0, stream>>>(q, wsK, wsVt, out);
  } else {
    attn_fwd<<<dim3(LQ / 64, NB), dim3(256), 0, stream>>>(q, k, v, out);
  }
}

// Round 7
// 75.549 us; speedup vs baseline: 1.1869x; 1.0190x over previous
//
#include <hip/hip_runtime.h>
#include <hip/hip_bf16.h>

typedef float f32x4 __attribute__((ext_vector_type(4)));
typedef float f32x16 __attribute__((ext_vector_type(16)));
typedef short bf16x8 __attribute__((ext_vector_type(8)));
typedef unsigned u32x4 __attribute__((ext_vector_type(4)));

constexpr int NB = 16, LQ = 2048, LK = 2048, D = 128, DV = 128;
constexpr int KVBLK = 64;
constexpr int NTH = 16;                         // 1024 keys per half / 64
constexpr float SCALE = 0.08838834764831843f;   // 1/sqrt(128)
constexpr float LOG2E = 1.4426950408889634f;
constexpr float QSCALE = SCALE * LOG2E;         // softmax in log2 domain

// ---------- helpers ----------
__device__ __forceinline__ unsigned short f2bfs(float f) {
  __hip_bfloat16 h = __float2bfloat16(f);      // RNE; pairs fuse to v_cvt_pk_bf16_f32
  return __builtin_bit_cast(unsigned short, h);
}

__device__ __forceinline__ unsigned short f2bf(float f) {
  unsigned int u = __float_as_uint(f);
  u += 0x7FFFu + ((u >> 16) & 1u);
  return (unsigned short)(u >> 16);
}

__device__ __forceinline__ int swz2(int row) {
  return (row ^ (row >> 1) ^ (row >> 3)) & 7;
}

// swap bits 2<->3 (involution). K rows staged at LDS row r hold global key
// row swap23(r); this makes each lane's S^T regs land exactly in its PV
// B-fragment slots (key of reg r per 32-tile = 16*(r>>3) + 8*hi + (r&7)).
__device__ __forceinline__ int swap23(int m) {
  return (m & ~12) | ((m & 4) << 1) | ((m & 8) >> 1);
}

typedef const __attribute__((address_space(1))) void* gas1_t;
typedef __attribute__((address_space(3))) void* las3_t;
__device__ __forceinline__ void gload16(const void* g, void* l) {
  __builtin_amdgcn_global_load_lds((gas1_t)g, (las3_t)l, 16, 0, 0);
}

__device__ __forceinline__ unsigned pk2(float lo, float hi) {
  unsigned short a = f2bfs(lo), b = f2bfs(hi);
  return (unsigned)a | ((unsigned)b << 16);
}

// pack one 32x32 S-tile (16 f32) into the two PV B-fragments — pure in-lane:
// with the swap23 K-row permutation, slot j of pb[ks] is simply s[8*ks + j].
__device__ __forceinline__ void mk_pb(const f32x16& s, bf16x8& pe, bf16x8& po) {
  u32x4 e = {pk2(s[0], s[1]), pk2(s[2], s[3]), pk2(s[4], s[5]), pk2(s[6], s[7])};
  pe = __builtin_bit_cast(bf16x8, e);
  u32x4 od = {pk2(s[8], s[9]), pk2(s[10], s[11]), pk2(s[12], s[13]), pk2(s[14], s[15])};
  po = __builtin_bit_cast(bf16x8, od);
}

// ---------- prepass: fp32 -> bf16 ----------
__global__ __launch_bounds__(256) void conv_bf16(const float* __restrict__ in,
                                                 unsigned short* __restrict__ out,
                                                 float scale) {
  int i = blockIdx.x * 256 + threadIdx.x;
  f32x4 a = ((const f32x4*)in)[2 * i];
  f32x4 b = ((const f32x4*)in)[2 * i + 1];
  bf16x8 r;
  #pragma unroll
  for (int j = 0; j < 4; ++j) {
    r[j]     = (short)f2bfs(a[j] * scale);
    r[4 + j] = (short)f2bfs(b[j] * scale);
  }
  ((bf16x8*)out)[i] = r;
}

// ---------- prepass: V[b][k][dv] fp32 -> Vt[b][dv][k] bf16 ----------
__global__ __launch_bounds__(256) void conv_vt(const float* __restrict__ v,
                                               unsigned short* __restrict__ vt) {
  __shared__ __align__(16) unsigned short tb[64 * 64];
  const int tid = threadIdx.x;
  const int k0 = blockIdx.x * 64, dv0 = blockIdx.y * 64, b = blockIdx.z;
  {
    const int kk = tid >> 2, dd0 = (tid & 3) * 16;
    const float* src = v + ((long)(b * LK + k0 + kk)) * DV + dv0 + dd0;
    f32x4 a0 = ((const f32x4*)src)[0];
    f32x4 a1 = ((const f32x4*)src)[1];
    f32x4 a2 = ((const f32x4*)src)[2];
    f32x4 a3 = ((const f32x4*)src)[3];
    bf16x8 r0, r1;
    #pragma unroll
    for (int j = 0; j < 4; ++j) {
      r0[j] = (short)f2bfs(a0[j]); r0[4 + j] = (short)f2bfs(a1[j]);
      r1[j] = (short)f2bfs(a2[j]); r1[4 + j] = (short)f2bfs(a3[j]);
    }
    int ch = dd0 >> 3;
    *(bf16x8*)&tb[kk * 64 + ((ch ^ swz2(kk)) << 3)] = r0;
    *(bf16x8*)&tb[kk * 64 + (((ch + 1) ^ swz2(kk)) << 3)] = r1;
  }
  __syncthreads();
  {
    const int dv = tid >> 2, ks = (tid & 3) * 16;
    bf16x8 w0, w1;
    #pragma unroll
    for (int j = 0; j < 8; ++j) {
      int r0 = ks + j, r1 = ks + 8 + j;
      w0[j] = (short)tb[r0 * 64 + (((dv >> 3) ^ swz2(r0)) << 3) + (dv & 7)];
      w1[j] = (short)tb[r1 * 64 + (((dv >> 3) ^ swz2(r1)) << 3) + (dv & 7)];
    }
    unsigned short* dst = vt + ((long)(b * DV + dv0 + dv)) * LK + k0 + ks;
    *(bf16x8*)dst = w0;
    *(bf16x8*)(dst + 8) = w1;
  }
}

// ---------- main: 32x32 swapped MFMA, in-register softmax, split-KV ----------
__global__ __launch_bounds__(512, 2) void attn_fwd5(
    const float* __restrict__ qp, const unsigned short* __restrict__ wsK,
    const unsigned short* __restrict__ wsVt, float* __restrict__ op) {
  // LDS 128 KB: per (half, buf): K[64][128] @ +0, Vt[128][64] @ +8192 (uint16)
  __shared__ __align__(16) unsigned short sm[65536];

  const int tid = threadIdx.x;
  const int wid = tid >> 6;        // 0..7
  const int h2  = wid >> 2;        // KV half
  const int lane = tid & 63;
  const int q32 = lane & 31;       // q-row within wave tile
  const int hi  = lane >> 5;       // k-slot half
  const int ht  = tid & 255;       // thread id within half-group

  // 256 blocks; 32 consecutive per XCD
  const int bid = blockIdx.x;
  const int sbid = (bid & 7) * 32 + (bid >> 3);
  const int b = sbid >> 4;
  const int qb = (sbid & 15) * 128;
  const int qwave = qb + (wid & 3) * 32;

  // ---- Q B-fragments: q=lane&31, d = st*16 + hi*8 + j; QSCALE folded ----
  bf16x8 aq[8];
  {
    const float* qrow = qp + ((long)(b * LQ + qwave + q32)) * D + hi * 8;
    #pragma unroll
    for (int st = 0; st < 8; ++st) {
      f32x4 x0 = *(const f32x4*)(qrow + st * 16);
      f32x4 x1 = *(const f32x4*)(qrow + st * 16 + 4);
      #pragma unroll
      for (int j = 0; j < 4; ++j) {
        aq[st][j]     = (short)f2bfs(x0[j] * QSCALE);
        aq[st][4 + j] = (short)f2bfs(x1[j] * QSCALE);
      }
    }
  }
  __builtin_amdgcn_sched_barrier(0);

  const unsigned short* kbatch = wsK + (long)b * LK * D;
  const unsigned short* vbatch = wsVt + (long)b * DV * LK;
  const int kvbase = h2 * 1024;
  const int lbase = h2 * 32768;

  // hoisted per-thread staging addresses (advance per tile by constant)
  const unsigned short* ksp[4];
  const unsigned short* vsp[4];
  unsigned ldk[4], ldv[4];
  #pragma unroll
  for (int it = 0; it < 4; ++it) {
    int ci = it * 256 + ht;
    int krow = ci >> 4, kc16 = ci & 15;
    // LDS row krow receives global key row swap23(krow) (P-routing trick);
    // chunk swizzle keyed on the LDS row (what the reader uses).
    ksp[it] = kbatch + (long)kvbase * D + swap23(krow) * D +
              ((kc16 ^ swz2(krow)) << 3);
    ldk[it] = lbase + ci * 8;
    int vrow = ci >> 3, vc8 = ci & 7;
    vsp[it] = vbatch + (long)vrow * LK + kvbase + ((vc8 ^ swz2(vrow)) << 3);
    ldv[it] = lbase + 8192 + ci * 8;
  }

  auto stage = [&](int buf, int t) {
    const int ko = t * (KVBLK * D);    // ushort elems
    const int vo = t * KVBLK;
    const int lb = buf * 16384;
    #pragma unroll
    for (int it = 0; it < 4; ++it)
      gload16(ksp[it] + ko, &sm[ldk[it] + lb]);
    #pragma unroll
    for (int it = 0; it < 4; ++it)
      gload16(vsp[it] + vo, &sm[ldv[it] + lb]);
  };

  stage(0, 0);
  stage(1, 1);

  f32x16 o[4];
  #pragma unroll
  for (int mt = 0; mt < 4; ++mt) o[mt] = (f32x16){};
  float m_s = -1e30f, l_s = 0.f;

  for (int t = 0; t < NTH; ++t) {
    if (t < NTH - 1) {
      asm volatile("s_waitcnt vmcnt(8)" ::: "memory");
    } else {
      asm volatile("s_waitcnt vmcnt(0)" ::: "memory");
    }
    __builtin_amdgcn_sched_barrier(0);
    __builtin_amdgcn_s_barrier();
    __builtin_amdgcn_sched_barrier(0);

    const int cur = t & 1;
    const int kb = lbase + cur * 16384, vb = kb + 8192;

    // ---- S^T = K Q^T: 2 M-tiles x 8 d-steps of mfma_32x32x16
    //      s{0,1}[reg] = S[key = 32*mt + 16*(reg>>3) + 8*hi + (reg&7)][q=q32]
    //      (swap23 staging permutation folded into the key identity)
    f32x16 s0 = (f32x16){}, s1 = (f32x16){};
    __builtin_amdgcn_s_setprio(1);
    #pragma unroll
    for (int st = 0; st < 8; ++st) {
      const int c16 = 2 * st + hi;
      const int r0 = q32;
      bf16x8 k0 = *(const bf16x8*)&sm[kb + r0 * 128 + ((c16 ^ swz2(r0)) << 3)];
      s0 = __builtin_amdgcn_mfma_f32_32x32x16_bf16(k0, aq[st], s0, 0, 0, 0);
      const int r1 = 32 + q32;
      bf16x8 k1 = *(const bf16x8*)&sm[kb + r1 * 128 + ((c16 ^ swz2(r1)) << 3)];
      s1 = __builtin_amdgcn_mfma_f32_32x32x16_bf16(k1, aq[st], s1, 0, 0, 0);
    }
    __builtin_amdgcn_s_setprio(0);

    // ---- in-register online softmax (log2 domain); lane owns q=q32
    float pm = s0[0];
    #pragma unroll
    for (int i = 1; i < 16; ++i) pm = fmaxf(pm, s0[i]);
    #pragma unroll
    for (int i = 0; i < 16; ++i) pm = fmaxf(pm, s1[i]);
    pm = fmaxf(pm, __shfl_xor(pm, 32));
    if (!__all(pm <= m_s + 8.0f)) {     // defer-max (T13)
      float mn = fmaxf(m_s, pm);
      float al = exp2f(m_s - mn);
      l_s *= al;
      #pragma unroll
      for (int mt = 0; mt < 4; ++mt)
        #pragma unroll
        for (int i = 0; i < 16; ++i) o[mt][i] *= al;
      m_s = mn;
    }
    float sum = 0.f;
    #pragma unroll
    for (int i = 0; i < 16; ++i) { s0[i] = exp2f(s0[i] - m_s); sum += s0[i]; }
    #pragma unroll
    for (int i = 0; i < 16; ++i) { s1[i] = exp2f(s1[i] - m_s); sum += s1[i]; }
    l_s += sum + __shfl_xor(sum, 32);

    // ---- pack P into PV B-fragments (pure in-lane, no cross-lane ops)
    bf16x8 pb[4];
    mk_pb(s0, pb[0], pb[1]);
    mk_pb(s1, pb[2], pb[3]);

    // ---- O^T += Vt P : 4 dv M-tiles x 4 k-steps
    __builtin_amdgcn_s_setprio(1);
    #pragma unroll
    for (int ks = 0; ks < 4; ++ks) {
      const int c8 = 2 * ks + hi;
      #pragma unroll
      for (int mt = 0; mt < 4; ++mt) {
        const int row = mt * 32 + q32;
        bf16x8 vf = *(const bf16x8*)&sm[vb + row * 64 + ((c8 ^ swz2(row)) << 3)];
        o[mt] = __builtin_amdgcn_mfma_f32_32x32x16_bf16(vf, pb[ks], o[mt], 0, 0, 0);
      }
    }
    __builtin_amdgcn_s_setprio(0);

    __builtin_amdgcn_sched_barrier(0);
    __builtin_amdgcn_s_barrier();
    __builtin_amdgcn_sched_barrier(0);

    if (t < NTH - 2) stage(cur, t + 2);
  }

  // ---- in-LDS combine of KV halves; o[mt][reg] = O^T[dv][q=q32],
  //      dv = 32*mt + (reg&3) + 8*(reg>>2) + 4*hi
  float* scr = (float*)sm;
  float* wreg = scr + (size_t)(wid & 3) * 4352;
  __syncthreads();
  if (h2 == 1) {
    #pragma unroll
    for (int j4 = 0; j4 < 16; ++j4) {
      const int mt = j4 >> 2, a = j4 & 3;
      f32x4 v = {o[mt][4 * a], o[mt][4 * a + 1], o[mt][4 * a + 2], o[mt][4 * a + 3]};
      *(f32x4*)&wreg[lane * 64 + ((j4 ^ (lane & 15)) << 2)] = v;
    }
    wreg[4096 + lane * 2] = m_s;
    wreg[4096 + lane * 2 + 1] = l_s;
  }
  __syncthreads();
  if (h2 == 0) {
    const float m1 = wreg[4096 + lane * 2];
    const float l1 = wreg[4096 + lane * 2 + 1];
    const float mm = fmaxf(m_s, m1);
    float a0 = exp2f(m_s - mm), a1 = exp2f(m1 - mm);
    const float inv = 1.f / (a0 * l_s + a1 * l1);
    a0 *= inv;
    a1 *= inv;
    float* dst = op + ((long)(b * LQ + qwave + q32)) * DV;
    #pragma unroll
    for (int j4 = 0; j4 < 16; ++j4) {
      const int mt = j4 >> 2, a = j4 & 3;
      f32x4 pv = *(const f32x4*)&wreg[lane * 64 + ((j4 ^ (lane & 15)) << 2)];
      f32x4 r;
      #pragma unroll
      for (int i = 0; i < 4; ++i) r[i] = a0 * o[mt][4 * a + i] + a1 * pv[i];
      *(f32x4*)&dst[32 * mt + 8 * a + 4 * hi] = r;
    }
  }
}

// ---------- legacy fallback (no-workspace path) ----------
__device__ __forceinline__ int swzc(int row, int c16) {
  return c16 ^ ((row ^ (row >> 3)) & 7);
}

__global__ __launch_bounds__(256, 2) void attn_fwd(
    const float* __restrict__ qp, const float* __restrict__ kp,
    const float* __restrict__ vp, float* __restrict__ op) {
  __shared__ __align__(16) unsigned short smm[28672];
  const int tid = threadIdx.x, wid = tid >> 6, lane = tid & 63;
  const int g = lane >> 4, c = lane & 15;
  const int b = blockIdx.y, qb = blockIdx.x * 64;
  const float* qg = qp + ((long)b * LQ + qb) * D;
  const float* kg = kp + (long)b * LK * D;
  const float* vg = vp + (long)b * LK * DV;
  #pragma unroll
  for (int it = 0; it < 4; ++it) {
    int ch = it * 256 + tid, row = ch >> 4, c16 = ch & 15;
    const float* src = qg + row * D + c16 * 8;
    f32x4 f0 = *(const f32x4*)(src);
    f32x4 f1 = *(const f32x4*)(src + 4);
    bf16x8 fr;
    #pragma unroll
    for (int j = 0; j < 4; ++j) {
      fr[j] = (short)f2bf(f0[j] * SCALE);
      fr[4 + j] = (short)f2bf(f1[j] * SCALE);
    }
    *(bf16x8*)&smm[row * 128 + swzc(row, c16) * 8] = fr;
  }
  __syncthreads();
  bf16x8 aq[4];
  #pragma unroll
  for (int ks = 0; ks < 4; ++ks) {
    int row = wid * 16 + c;
    aq[ks] = *(const bf16x8*)&smm[row * 128 + swzc(row, ks * 4 + g) * 8];
  }
  f32x4 o[8]; f32x4 fz = {0.f, 0.f, 0.f, 0.f};
  #pragma unroll
  for (int i = 0; i < 8; ++i) o[i] = fz;
  float m_r[4] = {-1e30f, -1e30f, -1e30f, -1e30f};
  float l_r[4] = {0.f, 0.f, 0.f, 0.f};
  const int pbase = 24576 + wid * 1024;
  for (int kv0 = 0; kv0 < LK; kv0 += KVBLK) {
    __syncthreads();
    const float* ksrc = kg + (long)kv0 * D;
    #pragma unroll
    for (int it = 0; it < 4; ++it) {
      int ch = it * 256 + tid, row = ch >> 4, c16 = ch & 15;
      const float* src = ksrc + row * D + c16 * 8;
      f32x4 f0 = *(const f32x4*)(src);
      f32x4 f1 = *(const f32x4*)(src + 4);
      bf16x8 fr;
      #pragma unroll
      for (int j = 0; j < 4; ++j) { fr[j] = (short)f2bf(f0[j]); fr[4 + j] = (short)f2bf(f1[j]); }
      *(bf16x8*)&smm[8192 + row * 128 + swzc(row, c16) * 8] = fr;
    }
    {
      const float* vsrc = vg + (long)kv0 * DV;
      int dvq = (tid & 31) * 4, kg8 = tid >> 5;
      f32x4 col[8];
      #pragma unroll
      for (int j = 0; j < 8; ++j) col[j] = *(const f32x4*)(vsrc + (kg8 * 8 + j) * DV + dvq);
      #pragma unroll
      for (int i = 0; i < 4; ++i) {
        int dv = dvq + i;
        bf16x8 fr;
        #pragma unroll
        for (int j = 0; j < 8; ++j) fr[j] = (short)f2bf(col[j][i]);
        *(bf16x8*)&smm[16384 + dv * 64 + swzc(dv, kg8) * 8] = fr;
      }
    }
    __syncthreads();
    f32x4 s[4];
    #pragma unroll
    for (int i = 0; i < 4; ++i) s[i] = fz;
    #pragma unroll
    for (int ks = 0; ks < 4; ++ks) {
      #pragma unroll
      for (int t = 0; t < 4; ++t) {
        int row = t * 16 + c;
        bf16x8 bk = *(const bf16x8*)&smm[8192 + row * 128 + swzc(row, ks * 4 + g) * 8];
        s[t] = __builtin_amdgcn_mfma_f32_16x16x32_bf16(aq[ks], bk, s[t], 0, 0, 0);
      }
    }
    #pragma unroll
    for (int r = 0; r < 4; ++r) {
      float pm = fmaxf(fmaxf(s[0][r], s[1][r]), fmaxf(s[2][r], s[3][r]));
      pm = fmaxf(pm, __shfl_xor(pm, 1));
      pm = fmaxf(pm, __shfl_xor(pm, 2));
      pm = fmaxf(pm, __shfl_xor(pm, 4));
      pm = fmaxf(pm, __shfl_xor(pm, 8));
      float mn = fmaxf(m_r[r], pm);
      float al = exp2f((m_r[r] - mn) * LOG2E);
      float sum = 0.f;
      #pragma unroll
      for (int t = 0; t < 4; ++t) {
        float p = exp2f((s[t][r] - mn) * LOG2E);
        s[t][r] = p; sum += p;
      }
      sum += __shfl_xor(sum, 1); sum += __shfl_xor(sum, 2);
      sum += __shfl_xor(sum, 4); sum += __shfl_xor(sum, 8);
      l_r[r] = l_r[r] * al + sum; m_r[r] = mn;
      #pragma unroll
      for (int dvt = 0; dvt < 8; ++dvt) o[dvt][r] *= al;
    }
    #pragma unroll
    for (int t = 0; t < 4; ++t)
      #pragma unroll
      for (int r = 0; r < 4; ++r) {
        int row = g * 4 + r, colx = c + 16 * t;
        smm[pbase + row * 64 + swzc(row, colx >> 3) * 8 + (colx & 7)] = f2bf(s[t][r]);
      }
    #pragma unroll
    for (int ks = 0; ks < 2; ++ks) {
      bf16x8 pa = *(const bf16x8*)&smm[pbase + c * 64 + swzc(c, ks * 4 + g) * 8];
      #pragma unroll
      for (int dvt = 0; dvt < 8; ++dvt) {
        int row = dvt * 16 + c;
        bf16x8 vb2 = *(const bf16x8*)&smm[16384 + row * 64 + swzc(row, ks * 4 + g) * 8];
        o[dvt] = __builtin_amdgcn_mfma_f32_16x16x32_bf16(pa, vb2, o[dvt], 0, 0, 0);
      }
    }
  }
  float* dst = op + ((long)b * LQ + qb + wid * 16) * DV;
  #pragma unroll
  for (int r = 0; r < 4; ++r) {
    float inv = 1.f / l_r[r];
    #pragma unroll
    for (int dvt = 0; dvt < 8; ++dvt)
      dst[(g * 4 + r) * DV + dvt * 16 + c] = o[dvt][r] * inv;
  }
}

extern "C" void kernel_launch(void* const* d_in, const int* in_sizes, int n_in,
                              void* d_out, int out_size, void* d_ws, size_t ws_size,
                              hipStream_t stream) {
  const float* q = (const float*)d_in[0];
  const float* k = (const float*)d_in[1];
  const float* v = (const float*)d_in[2];
  float* out = (float*)d_out;

  const size_t kelems = (size_t)NB * LK * D;
  const size_t need = kelems * 2 * 2;                 // K + Vt, bf16
  if (ws_size >= need) {
    unsigned short* wsK = (unsigned short*)d_ws;
    unsigned short* wsVt = wsK + kelems;
    conv_bf16<<<dim3((int)(kelems / 8 / 256)), dim3(256), 0, stream>>>(k, wsK, 1.0f);
    conv_vt<<<dim3(LK / 64, DV / 64, NB), dim3(256), 0, stream>>>(v, wsVt);
    attn_fwd5<<<dim3(NB * LQ / 128), dim3(512), 0, stream>>>(q, wsK, wsVt, out);
  } else {
    attn_fwd<<<dim3(LQ / 64, NB), dim3(256), 0, stream>>>(q, k, v, out);
  }
}